// Round 1
// baseline (164.539 us; speedup 1.0000x reference)
//
#include <hip/hip_runtime.h>
#include <math.h>

// Problem constants (reference: B=4, N=2048, TIMESTEPS=1000, speed=0.01)
#define TIMESTEPS 1000
constexpr int Bc = 4;
constexpr int Nc = 2048;
constexpr int EcI = Nc * (Nc - 1) / 2;   // 2,096,128 edges per batch (fits int)
constexpr int EG  = EcI / 4;             // 524,032 groups of 4 per batch

constexpr int BLOCKS_PER_B = 512;        // blocks per batch (grid = 4*512 = 2048)
constexpr int THREADS      = 256;
constexpr int GSTRIDE      = BLOCKS_PER_B * THREADS;  // 131,072 groups/iteration/batch
// ceil(EG / GSTRIDE) = 4 iterations; only the last is partially masked.

typedef int   i4v __attribute__((ext_vector_type(4)));
typedef float f4v __attribute__((ext_vector_type(4)));

// 4-byte-aligned 16B loads (adj/u group start is row-contiguous but j%4 arbitrary).
// clang emits a single global_load_dwordx4 where the HW unaligned path allows it;
// worst case it splits — never worse than the 4 scalar loads we had.
__device__ __forceinline__ i4v load_i4u(const int* p) {
    i4v r; __builtin_memcpy(&r, p, 16); return r;
}
__device__ __forceinline__ f4v load_f4u(const float* p) {
    f4v r; __builtin_memcpy(&r, p, 16); return r;
}

__global__ __launch_bounds__(256) void diff_loss_kernel(
    const int* __restrict__ adj, const int* __restrict__ t,
    const float* __restrict__ u, const float* __restrict__ q,
    double* __restrict__ partials)
{
    // One batch per 512-block slice: b is wave-uniform -> table constants live in
    // uniform registers, no LDS table, no per-group division.
    const int b  = blockIdx.x >> 9;
    const int lb = blockIdx.x & (BLOCKS_PER_B - 1);
    const int tb = t[b];

    // Qt[k] built with ts=k+1: flip = 0.5*(1 - 0.98^(k+1))
    const float f_t   = 0.5f * (1.0f - powf(0.98f, (float)(tb + 1)));
    const int   tpe   = (tb == 0) ? TIMESTEPS : tb;   // Qt[t-1], wrap -1 -> 999
    const float f_p   = 0.5f * (1.0f - powf(0.98f, (float)tpe));
    const float f0    = 0.5f * (1.0f - 0.98f);        // Qt[0] flip
    const float omf_t = 1.0f - f_t;

    const float p0   = f_t;                            // probs1 when a0==0
    const float p1   = omf_t;                          // probs1 when a0==1
    // q_target(a0,x) = lik1(x)*pri1(a0)/evid(a0,x); evid = (x==a0)?1-f_t:f_t
    const float qt00 = f0          * f_p          / omf_t;  // a0=0,x=0
    const float qt01 = (1.0f - f0) * f_p          / f_t;    // a0=0,x=1
    const float qt10 = f0          * (1.0f - f_p) / f_t;    // a0=1,x=0
    const float qt11 = (1.0f - f0) * (1.0f - f_p) / omf_t;  // a0=1,x=1

    const int*   adjb = adj + ((size_t)b << 22);
    const float* ub   = u   + ((size_t)b << 22);
    const float* qb   = q   + (size_t)b * EcI;

    double acc = 0.0;
    int g = lb * THREADS + threadIdx.x;

    #pragma unroll 2   // 2 groups in flight: 6 dwordx4 outstanding, VGPR stays <=64
    for (int it = 0; it < 4; ++it, g += GSTRIDE) {
        if (g < EG) {
            const int e0 = g << 2;                    // packed index, multiple of 4

            // invert triangular index: largest i with i*(i-1)/2 <= e0
            const float sf = sqrtf((float)(8 * e0 + 1));   // 8*e0+1 < 2^24: exact
            int i = (int)((1.0f + sf) * 0.5f);
            if (i * (i - 1) / 2 > e0)  --i;                // fixup rounding
            if (i * (i + 1) / 2 <= e0) ++i;
            const int j = e0 - i * (i - 1) / 2;            // 0 <= j < i

            const f4v q4 = *(const f4v*)(qb + e0);         // 16B aligned
            float s = 0.0f;

            if (j + 4 <= i) {
                // ---- fast path (~99.7%): whole group inside row i ----
                const int base = (i << 11) + j;
                const i4v av = load_i4u(adjb + base);
                const f4v uv = load_f4u(ub   + base);
                #pragma unroll
                for (int k = 0; k < 4; ++k) {
                    const int   a0 = av[k];
                    const float ps = a0 ? p1 : p0;
                    const bool  x  = (uv[k] < ps);
                    const float t0 = x ? qt01 : qt00;
                    const float t1 = x ? qt11 : qt10;
                    const float qtv = a0 ? t1 : t0;
                    const float qv  = q4[k];
                    s += fmaxf(qv, 0.0f) - qv * qtv
                       + __logf(1.0f + __expf(-fabsf(qv)));
                }
            } else {
                // ---- rare path: group crosses a row boundary (scalar, as before) ----
                int ii = i, jj = j;
                #pragma unroll
                for (int k = 0; k < 4; ++k) {
                    const bool adv = (jj >= ii);
                    ii += adv;
                    jj = adv ? 0 : jj;
                    const int base = (ii << 11) + jj;
                    const int   a0 = adjb[base];
                    const float uu = ub[base];
                    const float ps = a0 ? p1 : p0;
                    const bool  x  = (uu < ps);
                    const float t0 = x ? qt01 : qt00;
                    const float t1 = x ? qt11 : qt10;
                    const float qtv = a0 ? t1 : t0;
                    const float qv  = q4[k];
                    s += fmaxf(qv, 0.0f) - qv * qtv
                       + __logf(1.0f + __expf(-fabsf(qv)));
                    ++jj;
                }
            }
            acc += (double)s;
        }
    }

    // wave (64) shuffle reduce, then cross-wave via LDS
    for (int off = 32; off > 0; off >>= 1)
        acc += __shfl_down(acc, off, 64);
    __shared__ double wsum[4];
    const int lane = threadIdx.x & 63, wid = threadIdx.x >> 6;
    if (lane == 0) wsum[wid] = acc;
    __syncthreads();
    if (threadIdx.x == 0)
        partials[blockIdx.x] = wsum[0] + wsum[1] + wsum[2] + wsum[3];
}

// Reduce per-block partials, write mean as f32.
__global__ __launch_bounds__(256) void final_reduce_kernel(
    const double* __restrict__ partials, int nb, float* __restrict__ out)
{
    double acc = 0.0;
    for (int idx = threadIdx.x; idx < nb; idx += blockDim.x)
        acc += partials[idx];
    for (int off = 32; off > 0; off >>= 1)
        acc += __shfl_down(acc, off, 64);
    __shared__ double wsum[4];
    const int lane = threadIdx.x & 63, wid = threadIdx.x >> 6;
    if (lane == 0) wsum[wid] = acc;
    __syncthreads();
    if (threadIdx.x == 0)
        out[0] = (float)((wsum[0] + wsum[1] + wsum[2] + wsum[3]) /
                         ((double)Bc * (double)EcI));
}

extern "C" void kernel_launch(void* const* d_in, const int* in_sizes, int n_in,
                              void* d_out, int out_size, void* d_ws, size_t ws_size,
                              hipStream_t stream) {
    const int*   adj = (const int*)d_in[0];   // adj_start (B,N,N) int32
    const int*   t   = (const int*)d_in[1];   // t (B,) int32
    const float* u   = (const float*)d_in[2]; // u (B,N,N) f32
    const float* q   = (const float*)d_in[3]; // q_approx (B,E) f32
    float*  out      = (float*)d_out;
    double* partials = (double*)d_ws;         // NB doubles (16 KB)

    const int NB = Bc * BLOCKS_PER_B;         // 2048
    diff_loss_kernel<<<NB, THREADS, 0, stream>>>(adj, t, u, q, partials);
    final_reduce_kernel<<<1, 256, 0, stream>>>(partials, NB, out);
}

// Round 2
// 163.335 us; speedup vs baseline: 1.0074x; 1.0074x over previous
//
#include <hip/hip_runtime.h>
#include <math.h>

// Problem constants (reference: B=4, N=2048, TIMESTEPS=1000, speed=0.01)
#define TIMESTEPS 1000
constexpr int Bc  = 4;
constexpr int Nc  = 2048;
constexpr int EcI = Nc * (Nc - 1) / 2;   // 2,096,128 edges per batch
constexpr int THREADS = 256;
constexpr int NB  = 2048;                // 4 batches x 512 block-slices (2 row-pairs each)

typedef int   i4v __attribute__((ext_vector_type(4)));
typedef float f4v __attribute__((ext_vector_type(4)));

__device__ __forceinline__ int imin(int a, int b) { return a < b ? a : b; }

// One 4-column group: row-pair decomposition.
//   pair p covers row a=p+1 (len a) and row rb=2047-p (len rb; 0 for p=1023 dup).
//   groups 0..Ga-1 are row a (j = 4*gg), groups Ga.. are row rb (j = 4*(gg-Ga)).
//   adj/u loads: j % 4 == 0 -> genuinely 16B-aligned dwordx4.
//   q load: packed index tri(row)+j, 4B-aligned -> 4 scalar dwords (lines reused
//   across k, L1-resident). Per-k OOB clamped, validity masked arithmetically.
struct Grp {
    i4v av; f4v uv;
    float q0, q1, q2, q3;
    int jg, len;
};

__device__ __forceinline__ Grp load_group(
    const int* __restrict__ adjb, const float* __restrict__ ub,
    const float* __restrict__ qb, int gg, int la, int lb, int rb, int Ga)
{
    Grp g;
    const bool ina = gg < Ga;
    const int row  = ina ? la : rb;            // row index (row a index == la)
    g.len = ina ? la : lb;
    g.jg  = (ina ? gg : (gg - Ga)) << 2;
    const int base = (row << 11) + g.jg;       // 16B-aligned element offset
    g.av = *(const i4v*)(adjb + base);         // global_load_dwordx4
    g.uv = *(const f4v*)(ub + base);           // global_load_dwordx4
    const int tri = (row * (row - 1)) >> 1;    // fits int (row <= 2047)
    const int e   = tri + g.jg;
    g.q0 = qb[imin(e,     EcI - 1)];
    g.q1 = qb[imin(e + 1, EcI - 1)];
    g.q2 = qb[imin(e + 2, EcI - 1)];
    g.q3 = qb[imin(e + 3, EcI - 1)];
    return g;
}

__device__ __forceinline__ float grp_term(const Grp& g,
    float p0, float p1, float qt00, float qt01, float qt10, float qt11)
{
    const float qs[4] = {g.q0, g.q1, g.q2, g.q3};
    float s = 0.0f;
    #pragma unroll
    for (int k = 0; k < 4; ++k) {
        const int   a0 = g.av[k];
        const float ps = a0 ? p1 : p0;
        const bool  x  = g.uv[k] < ps;
        const float t0 = x ? qt01 : qt00;
        const float t1 = x ? qt11 : qt10;
        const float qt = a0 ? t1 : t0;
        const float qv = qs[k];
        const float term = fmaxf(qv, 0.0f) - qv * qt
                         + __logf(1.0f + __expf(-fabsf(qv)));
        s += (g.jg + k < g.len) ? term : 0.0f;   // branch-free row-end mask
    }
    return s;
}

__global__ __launch_bounds__(256, 8) void diff_loss_kernel(
    const int* __restrict__ adj, const int* __restrict__ t,
    const float* __restrict__ u, const float* __restrict__ q,
    double* __restrict__ partials)
{
    const int blk = blockIdx.x;
    const int b   = blk >> 9;                 // batch
    const int ip  = blk & 511;                // handles pairs 2*ip, 2*ip+1
    const int tb  = t[b];

    // Qt[k] built with ts=k+1: flip = 0.5*(1 - 0.98^(k+1))
    const float f_t   = 0.5f * (1.0f - powf(0.98f, (float)(tb + 1)));
    const int   tpe   = (tb == 0) ? TIMESTEPS : tb;   // Qt[t-1], wrap -1 -> 999
    const float f_p   = 0.5f * (1.0f - powf(0.98f, (float)tpe));
    const float f0    = 0.01f;                        // Qt[0] flip = 0.5*(1-0.98)
    const float omf_t = 1.0f - f_t;

    const float p0   = f_t;                            // probs1 when a0==0
    const float p1   = omf_t;                          // probs1 when a0==1
    const float qt00 = f0          * f_p          / omf_t;  // a0=0,x=0
    const float qt01 = (1.0f - f0) * f_p          / f_t;    // a0=0,x=1
    const float qt10 = f0          * (1.0f - f_p) / f_t;    // a0=1,x=0
    const float qt11 = (1.0f - f0) * (1.0f - f_p) / omf_t;  // a0=1,x=1

    const int*   adjb = adj + ((size_t)b << 22);
    const float* ub   = u   + ((size_t)b << 22);
    const float* qb   = q   + (size_t)b * EcI;

    const int tid = threadIdx.x;
    double acc = 0.0;

    // Main path: branch-free, straight-line -> loads of both groups of a pair
    // (and across pairs) can stay in flight.
    #pragma unroll
    for (int pp = 0; pp < 2; ++pp) {
        const int p  = 2 * ip + pp;
        const int la = p + 1;                     // row a index and length
        const int rb = 2047 - p;                  // row b index
        const int lb = (p == 1023) ? 0 : rb;      // row b length (dup row masked)
        const int Ga = (la + 3) >> 2;             // aligned groups in row a

        Grp g0 = load_group(adjb, ub, qb, tid,       la, lb, rb, Ga);
        Grp g1 = load_group(adjb, ub, qb, tid + 256, la, lb, rb, Ga);
        acc += (double)grp_term(g0, p0, p1, qt00, qt01, qt10, qt11);
        acc += (double)grp_term(g1, p0, p1, qt00, qt01, qt10, qt11);
    }

    // Tail: the 513th group per pair (exists iff row-a length % 4 != 0).
    if (tid == 0) {
        #pragma unroll
        for (int pp = 0; pp < 2; ++pp) {
            const int p  = 2 * ip + pp;
            const int la = p + 1;
            if (la & 3) {
                const int rb = 2047 - p;
                const int lb = (p == 1023) ? 0 : rb;
                const int Ga = (la + 3) >> 2;
                Grp gt = load_group(adjb, ub, qb, 512, la, lb, rb, Ga);
                acc += (double)grp_term(gt, p0, p1, qt00, qt01, qt10, qt11);
            }
        }
    }

    // wave (64) shuffle reduce, then cross-wave via LDS
    for (int off = 32; off > 0; off >>= 1)
        acc += __shfl_down(acc, off, 64);
    __shared__ double wsum[4];
    const int lane = threadIdx.x & 63, wid = threadIdx.x >> 6;
    if (lane == 0) wsum[wid] = acc;
    __syncthreads();
    if (threadIdx.x == 0)
        partials[blockIdx.x] = wsum[0] + wsum[1] + wsum[2] + wsum[3];
}

// Reduce per-block partials, write mean as f32.
__global__ __launch_bounds__(256) void final_reduce_kernel(
    const double* __restrict__ partials, int nb, float* __restrict__ out)
{
    double acc = 0.0;
    for (int idx = threadIdx.x; idx < nb; idx += blockDim.x)
        acc += partials[idx];
    for (int off = 32; off > 0; off >>= 1)
        acc += __shfl_down(acc, off, 64);
    __shared__ double wsum[4];
    const int lane = threadIdx.x & 63, wid = threadIdx.x >> 6;
    if (lane == 0) wsum[wid] = acc;
    __syncthreads();
    if (threadIdx.x == 0)
        out[0] = (float)((wsum[0] + wsum[1] + wsum[2] + wsum[3]) /
                         ((double)Bc * (double)EcI));
}

extern "C" void kernel_launch(void* const* d_in, const int* in_sizes, int n_in,
                              void* d_out, int out_size, void* d_ws, size_t ws_size,
                              hipStream_t stream) {
    const int*   adj = (const int*)d_in[0];   // adj_start (B,N,N) int32
    const int*   t   = (const int*)d_in[1];   // t (B,) int32
    const float* u   = (const float*)d_in[2]; // u (B,N,N) f32
    const float* q   = (const float*)d_in[3]; // q_approx (B,E) f32
    float*  out      = (float*)d_out;
    double* partials = (double*)d_ws;         // NB doubles (16 KB)

    diff_loss_kernel<<<NB, THREADS, 0, stream>>>(adj, t, u, q, partials);
    final_reduce_kernel<<<1, 256, 0, stream>>>(partials, NB, out);
}